// Round 1
// baseline (294.047 us; speedup 1.0000x reference)
//
#include <hip/hip_runtime.h>
#include <math.h>

#define N_ANCHORS 2048
#define BLOCK 256

__global__ __launch_bounds__(BLOCK) void det_kernel(
    const float* __restrict__ loc,    // (8, 2048, 2)
    const float* __restrict__ cls,    // (8, 2048, 5)
    const float* __restrict__ defs,   // (2048, 2)
    float* __restrict__ out)          // (8, 4, 2048, 3)
{
#pragma clang fp contract(off)
    const int tid = threadIdx.x;
    const int bc  = blockIdx.x;   // 0..31
    const int b   = bc >> 2;
    const int c   = bc & 3;       // maps to softmax component c+1

    __shared__ float         s_sc[N_ANCHORS];
    __shared__ int           s_id[N_ANCHORS];
    __shared__ float         s_bs[N_ANCHORS];   // box start, by ORIGINAL index
    __shared__ float         s_be[N_ANCHORS];   // box end,   by ORIGINAL index
    __shared__ unsigned char s_kp[N_ANCHORS];   // keep flag, by SORTED position
    __shared__ int           s_cnt;

    // ---- load + softmax + decode ----
    for (int n = tid; n < N_ANCHORS; n += BLOCK) {
        const float* cp = cls + ((size_t)b * N_ANCHORS + n) * 5;
        float x0 = cp[0], x1 = cp[1], x2 = cp[2], x3 = cp[3], x4 = cp[4];
        float m  = fmaxf(fmaxf(fmaxf(fmaxf(x0, x1), x2), x3), x4);
        float e0 = expf(x0 - m), e1 = expf(x1 - m), e2 = expf(x2 - m),
              e3 = expf(x3 - m), e4 = expf(x4 - m);
        float sum = e0 + e1 + e2 + e3 + e4;
        float ec  = (c == 0) ? e1 : (c == 1) ? e2 : (c == 2) ? e3 : e4;
        float score = ec / sum;

        const float* lp = loc + ((size_t)b * N_ANCHORS + n) * 2;
        float l0 = lp[0], l1 = lp[1];
        float d0 = defs[n * 2 + 0], d1 = defs[n * 2 + 1];
        float cc = d0 + l0 * d1;          // contract(off): separate mul+add like numpy
        float w  = d1 * expf(l1);
        float bs = cc - 0.5f * w;
        float be = cc + 0.5f * w;
        s_bs[n] = bs;
        s_be[n] = be;

        bool valid = score > 0.3f;        // THRESH
        s_sc[n] = valid ? score : -INFINITY;
        s_id[n] = n;
    }
    if (tid == 0) s_cnt = 0;
    __syncthreads();

    // ---- bitonic sort: score descending, index ascending on ties ----
    // Strict total order == JAX stable argsort(-masked) result.
    for (int k = 2; k <= N_ANCHORS; k <<= 1) {
        for (int j = k >> 1; j > 0; j >>= 1) {
            for (int i = tid; i < N_ANCHORS; i += BLOCK) {
                int ixj = i ^ j;
                if (ixj > i) {
                    float si = s_sc[i], sj = s_sc[ixj];
                    int   ii = s_id[i], ij = s_id[ixj];
                    bool j_before_i = (sj > si) || (sj == si && ij < ii);
                    bool i_before_j = (si > sj) || (si == sj && ii < ij);
                    bool dir = ((i & k) == 0);
                    bool doSwap = dir ? j_before_i : i_before_j;
                    if (doSwap) {
                        s_sc[i] = sj; s_sc[ixj] = si;
                        s_id[i] = ij; s_id[ixj] = ii;
                    }
                }
            }
            __syncthreads();
        }
    }

    // ---- count valid (sorted: valid occupy positions [0, V)) + init keep ----
    int local = 0;
    for (int i = tid; i < N_ANCHORS; i += BLOCK) {
        bool v = (s_sc[i] != -INFINITY);
        if (v) local++;
        s_kp[i] = v ? 1 : 0;
    }
    atomicAdd(&s_cnt, local);
    __syncthreads();
    const int V = s_cnt;

    // ---- greedy NMS (sequential over sorted positions) ----
    volatile unsigned char* kp = s_kp;
    for (int i = 0; i < V; ++i) {
        if (kp[i]) {
            int   idi = s_id[i];
            float bsi = s_bs[idi], bei = s_be[idi];
            float li  = bei - bsi;
            for (int j = i + 1 + tid; j < V; j += BLOCK) {
                if (kp[j]) {
                    int   idj = s_id[j];
                    float bsj = s_bs[idj], bej = s_be[idj];
                    float inter = fminf(bei, bej) - fmaxf(bsi, bsj);
                    inter = fmaxf(inter, 0.0f);                    // clip(x, 0)
                    float uni = li + (bej - bsj) - inter;
                    float iou = inter / fmaxf(uni, 1e-12f);
                    if (iou > 0.5f) kp[j] = 0;                     // OVERLAP
                }
            }
        }
        __syncthreads();
    }

    // ---- in_range mask (applied AFTER nms, affects output only) + scatter ----
    for (int i = tid; i < N_ANCHORS; i += BLOCK) {
        int   n   = s_id[i];
        float bsn = s_bs[n], ben = s_be[n];
        bool keep = s_kp[i] && (bsn > -10.0f) && (ben < 10.0f);
        size_t base = ((size_t)bc * N_ANCHORS + n) * 3;
        out[base + 0] = keep ? bsn : 0.0f;
        out[base + 1] = keep ? ben : 0.0f;
        out[base + 2] = keep ? s_sc[i] : 0.0f;   // finite whenever keep
    }
}

extern "C" void kernel_launch(void* const* d_in, const int* in_sizes, int n_in,
                              void* d_out, int out_size, void* d_ws, size_t ws_size,
                              hipStream_t stream) {
    const float* loc  = (const float*)d_in[0];  // localizations (8,2048,2)
    const float* cls  = (const float*)d_in[1];  // classifications (8,2048,5)
    const float* defs = (const float*)d_in[2];  // localizations_default (2048,2)
    float* out = (float*)d_out;                 // (8,4,2048,3) fp32
    det_kernel<<<32, BLOCK, 0, stream>>>(loc, cls, defs, out);
}